// Round 15
// baseline (100.492 us; speedup 1.0000x reference)
//
#include <hip/hip_runtime.h>

// hnode_prompt_layer_feature_cat_edge
// out[d, 0:128]   = (sum_{e: dst[e]=d} emb[src[e]]) * w
// out[d, 128:160] =  sum_{e: dst[e]=d} e_feat[e]
//
// R15 = R14 structure, gather reshaped to ONE NODE PER 32-LANE HALF-WAVE:
//  - 2 nodes/wave, each half independent: one bucket-load instruction
//    fetches two nodes' rows; all 64 lanes store (R14 idled half at store);
//    no cross-half xor-32 reduces; 25k waves instead of 50k.
//  - per half: 4-edge unmasked main blocks + ONE masked 4-edge tail
//    (R9's proven clamp/mask discipline at width 32).
//  - width-32 shfls only read the half's own lanes -> safe under cross-half
//    exec divergence (different trip counts). NOT R7's mistake: each lane
//    serves exactly one node, per-lane state identical to R12.
//  - cold ovf drain per-half (no cross-half reduce -> no double-count).

#define D_FT 128
#define D_E 32
#define D_OUT (D_FT + D_E)
#define CAP 32

typedef float f32x4 __attribute__((ext_vector_type(4)));
typedef int   i32x2 __attribute__((ext_vector_type(2)));

__global__ void place_bucket_kernel(const int* __restrict__ src_idx,
                                    const int* __restrict__ dst_idx,
                                    int* __restrict__ cursor,
                                    i32x2* __restrict__ bucket,
                                    int* __restrict__ ovf,
                                    int* __restrict__ ovf_cnt, int E) {
    int i = blockIdx.x * blockDim.x + threadIdx.x;
    if (i >= E) return;
    int d = dst_idx[i];
    int slot = atomicAdd(&cursor[d], 1);
    if (slot < CAP) {
        i32x2 pr; pr.x = src_idx[i]; pr.y = i;
        bucket[(size_t)d * CAP + slot] = pr;
    } else {
        int p = atomicAdd(ovf_cnt, 1);
        ovf[p] = i;
    }
}

__global__ void gather_bucket_kernel(const float* __restrict__ emb,
                                     const float* __restrict__ e_feat,
                                     const float* __restrict__ w,
                                     const int* __restrict__ cursor,
                                     const i32x2* __restrict__ bucket,
                                     const int* __restrict__ src_idx,
                                     const int* __restrict__ dst_idx,
                                     const int* __restrict__ ovf,
                                     const int* __restrict__ ovf_cnt,
                                     float* __restrict__ out, int N) {
    int g = (blockIdx.x * blockDim.x + threadIdx.x) >> 5;   // node = 32-lane group
    if (g >= N) return;                                     // group-uniform exit
    const int q  = threadIdx.x & 31;  // float4 slot within the 128-wide row
    const int qg = q >> 3;            // e_feat edge-subgroup 0..3
    const int ql = q & 7;             // float4 slot within e_feat row

    // cursor and bucket loads issue independently. Slots >= cnt hold stale
    // data but are never consumed (clamped shfl sources, masked loads).
    i32x2 pr = bucket[(size_t)g * CAP + q];
    int cnt_raw = cursor[g];
    int cnt = cnt_raw > CAP ? CAP : cnt_raw;

    float4 accft = make_float4(0.f, 0.f, 0.f, 0.f);
    float4 acce  = make_float4(0.f, 0.f, 0.f, 0.f);  // partial for subgroup qg

    int i = 0;
    // ---- main loop: unmasked 4-edge blocks (5 loads in flight per half,
    //      10 per wave with both halves issuing from shared instructions) ----
    for (; i + 4 <= cnt; i += 4) {
        // convergent within the group: sources i..i+3, i+qg <= cnt-1 valid
        int s0 = __shfl(pr.x, i + 0, 32);
        int s1 = __shfl(pr.x, i + 1, 32);
        int s2 = __shfl(pr.x, i + 2, 32);
        int s3 = __shfl(pr.x, i + 3, 32);
        int ee = __shfl(pr.y, i + qg, 32);
        float4 v0 = *reinterpret_cast<const float4*>(emb + (size_t)s0 * D_FT + q * 4);
        float4 v1 = *reinterpret_cast<const float4*>(emb + (size_t)s1 * D_FT + q * 4);
        float4 v2 = *reinterpret_cast<const float4*>(emb + (size_t)s2 * D_FT + q * 4);
        float4 v3 = *reinterpret_cast<const float4*>(emb + (size_t)s3 * D_FT + q * 4);
        f32x4 a = __builtin_nontemporal_load(
            reinterpret_cast<const f32x4*>(e_feat + (size_t)ee * D_E + ql * 4));
        accft.x += (v0.x + v1.x) + (v2.x + v3.x);
        accft.y += (v0.y + v1.y) + (v2.y + v3.y);
        accft.z += (v0.z + v1.z) + (v2.z + v3.z);
        accft.w += (v0.w + v1.w) + (v2.w + v3.w);
        acce.x += a.x; acce.y += a.y; acce.z += a.z; acce.w += a.w;
    }
    // ---- remainder (cnt - i in [1,3]): ONE masked 4-edge block ----
    // Group-uniform entry; shfl sources clamped to [0, cnt-1] (valid, active
    // lanes of THIS half); redundant loads hit the same row (L1); fma masks
    // zero the redundant contributions.
    if (i < cnt) {
        const int c1 = cnt - 1;
        int t0 = i + 0, t1 = i + 1, t2 = i + 2, t3 = i + 3, te = i + qg;
        int s0 = __shfl(pr.x, t0 < c1 ? t0 : c1, 32);
        int s1 = __shfl(pr.x, t1 < c1 ? t1 : c1, 32);
        int s2 = __shfl(pr.x, t2 < c1 ? t2 : c1, 32);
        int s3 = __shfl(pr.x, t3 < c1 ? t3 : c1, 32);
        int ee = __shfl(pr.y, te < c1 ? te : c1, 32);
        float4 v0 = *reinterpret_cast<const float4*>(emb + (size_t)s0 * D_FT + q * 4);
        float4 v1 = *reinterpret_cast<const float4*>(emb + (size_t)s1 * D_FT + q * 4);
        float4 v2 = *reinterpret_cast<const float4*>(emb + (size_t)s2 * D_FT + q * 4);
        float4 v3 = *reinterpret_cast<const float4*>(emb + (size_t)s3 * D_FT + q * 4);
        f32x4 a = __builtin_nontemporal_load(
            reinterpret_cast<const f32x4*>(e_feat + (size_t)ee * D_E + ql * 4));
        float m0 = (t0 < cnt) ? 1.f : 0.f;
        float m1 = (t1 < cnt) ? 1.f : 0.f;
        float m2 = (t2 < cnt) ? 1.f : 0.f;
        float m3 = (t3 < cnt) ? 1.f : 0.f;
        float me = (te < cnt) ? 1.f : 0.f;
        accft.x = fmaf(v0.x, m0, accft.x); accft.y = fmaf(v0.y, m0, accft.y);
        accft.z = fmaf(v0.z, m0, accft.z); accft.w = fmaf(v0.w, m0, accft.w);
        accft.x = fmaf(v1.x, m1, accft.x); accft.y = fmaf(v1.y, m1, accft.y);
        accft.z = fmaf(v1.z, m1, accft.z); accft.w = fmaf(v1.w, m1, accft.w);
        accft.x = fmaf(v2.x, m2, accft.x); accft.y = fmaf(v2.y, m2, accft.y);
        accft.z = fmaf(v2.z, m2, accft.z); accft.w = fmaf(v2.w, m2, accft.w);
        accft.x = fmaf(v3.x, m3, accft.x); accft.y = fmaf(v3.y, m3, accft.y);
        accft.z = fmaf(v3.z, m3, accft.z); accft.w = fmaf(v3.w, m3, accft.w);
        acce.x = fmaf(a.x, me, acce.x); acce.y = fmaf(a.y, me, acce.y);
        acce.z = fmaf(a.z, me, acce.z); acce.w = fmaf(a.w, me, acce.w);
    }

    // ---- COLD: drain this node's overflow edges (raw degree > CAP) ----
    // Group-uniform branch, ~never taken. All 32 lanes of the group
    // participate (no cross-half reduce exists to double-count).
    if (cnt_raw > CAP) {
        int n = *ovf_cnt;
        for (int k = 0; k < n; ++k) {
            int eid = ovf[k];
            if (dst_idx[eid] == g) {
                int s = src_idx[eid];
                float4 v = *reinterpret_cast<const float4*>(emb + (size_t)s * D_FT + q * 4);
                accft.x += v.x; accft.y += v.y; accft.z += v.z; accft.w += v.w;
                if (q < 8) {   // qg==0, ql==q: slot-q partial, summed by xor 8/16
                    f32x4 a = *reinterpret_cast<const f32x4*>(e_feat + (size_t)eid * D_E + q * 4);
                    acce.x += a.x; acce.y += a.y; acce.z += a.z; acce.w += a.w;
                }
            }
        }
    }

    // reduce e partials across the 4 edge-subgroups (within the half)
    acce.x += __shfl_xor(acce.x, 8, 32);
    acce.y += __shfl_xor(acce.y, 8, 32);
    acce.z += __shfl_xor(acce.z, 8, 32);
    acce.w += __shfl_xor(acce.w, 8, 32);
    acce.x += __shfl_xor(acce.x, 16, 32);
    acce.y += __shfl_xor(acce.y, 16, 32);
    acce.z += __shfl_xor(acce.z, 16, 32);
    acce.w += __shfl_xor(acce.w, 16, 32);

    // store: ALL lanes of the group write their node's row
    float4 wv = *reinterpret_cast<const float4*>(w + q * 4);
    float* o = out + (size_t)g * D_OUT;
    f32x4 r; r.x = accft.x * wv.x; r.y = accft.y * wv.y;
             r.z = accft.z * wv.z; r.w = accft.w * wv.w;
    __builtin_nontemporal_store(r, reinterpret_cast<f32x4*>(o + q * 4));
    if (q < 8) {
        f32x4 re; re.x = acce.x; re.y = acce.y; re.z = acce.z; re.w = acce.w;
        __builtin_nontemporal_store(re, reinterpret_cast<f32x4*>(o + D_FT + q * 4));
    }
}

// ---- fallback (R1 atomic path) if ws too small ----
__global__ void scatter_ft_kernel(const float* __restrict__ emb, const float* __restrict__ w,
                                  const int* __restrict__ src_idx, const int* __restrict__ dst_idx,
                                  float* __restrict__ out, int n_items) {
    int idx = blockIdx.x * blockDim.x + threadIdx.x;
    if (idx >= n_items) return;
    int e = idx >> 5, q = idx & 31;
    int s = src_idx[e], d = dst_idx[e];
    const float4 v  = *reinterpret_cast<const float4*>(emb + (size_t)s * D_FT + q * 4);
    const float4 wv = *reinterpret_cast<const float4*>(w + q * 4);
    float* o = out + (size_t)d * D_OUT + q * 4;
    atomicAdd(o + 0, v.x * wv.x); atomicAdd(o + 1, v.y * wv.y);
    atomicAdd(o + 2, v.z * wv.z); atomicAdd(o + 3, v.w * wv.w);
}
__global__ void scatter_e_kernel(const float* __restrict__ e_feat, const int* __restrict__ dst_idx,
                                 float* __restrict__ out, int n_items) {
    int idx = blockIdx.x * blockDim.x + threadIdx.x;
    if (idx >= n_items) return;
    int e = idx >> 3, q = idx & 7;
    int d = dst_idx[e];
    const float4 v = *reinterpret_cast<const float4*>(e_feat + (size_t)e * D_E + q * 4);
    float* o = out + (size_t)d * D_OUT + D_FT + q * 4;
    atomicAdd(o + 0, v.x); atomicAdd(o + 1, v.y);
    atomicAdd(o + 2, v.z); atomicAdd(o + 3, v.w);
}

extern "C" void kernel_launch(void* const* d_in, const int* in_sizes, int n_in,
                              void* d_out, int out_size, void* d_ws, size_t ws_size,
                              hipStream_t stream) {
    const float* emb    = (const float*)d_in[0];   // [N, 128]
    const float* e_feat = (const float*)d_in[1];   // [E, 32]
    const float* w      = (const float*)d_in[2];   // [1, 128]
    const int*   src    = (const int*)d_in[3];     // [E]
    const int*   dst    = (const int*)d_in[4];     // [E]
    float* out = (float*)d_out;                    // [N, 160]

    const int E = in_sizes[3];
    const int N = out_size / D_OUT;

    // ws layout: cursor[N] | ovf_cnt[1] | pad[1] | bucket[N*CAP] i32x2 | ovf[E]
    size_t ints_head = (size_t)N + 2;
    size_t need = ints_head * 4 + (size_t)N * CAP * 8 + (size_t)E * 4;

    if (ws_size >= need) {
        int*   cursor  = (int*)d_ws;
        int*   ovf_cnt = cursor + N;
        i32x2* bucket  = (i32x2*)(cursor + ints_head);
        int*   ovf     = (int*)(bucket + (size_t)N * CAP);

        hipMemsetAsync(cursor, 0, ints_head * sizeof(int), stream);
        place_bucket_kernel<<<(E + 255) / 256, 256, 0, stream>>>(
            src, dst, cursor, bucket, ovf, ovf_cnt, E);
        gather_bucket_kernel<<<((size_t)N * 32 + 255) / 256, 256, 0, stream>>>(
            emb, e_feat, w, cursor, bucket, src, dst, ovf, ovf_cnt, out, N);
    } else {
        hipMemsetAsync(d_out, 0, (size_t)out_size * sizeof(float), stream);
        int items_ft = E * 32, items_e = E * 8;
        scatter_ft_kernel<<<(items_ft + 255) / 256, 256, 0, stream>>>(emb, w, src, dst, out, items_ft);
        scatter_e_kernel<<<(items_e + 255) / 256, 256, 0, stream>>>(e_feat, dst, out, items_e);
    }
}